// Round 5
// baseline (116.645 us; speedup 1.0000x reference)
//
#include <hip/hip_runtime.h>
#include <hip/hip_bf16.h>
#include <math.h>

#define D 8192

__device__ __forceinline__ float wave_sum(float v) {
    #pragma unroll
    for (int o = 32; o > 0; o >>= 1) v += __shfl_xor(v, o, 64);
    return v;
}

// ===== K1 fused: blocks 0..511: one teacher row each (1024 thr):
//       topk8 -> weights -> gather pred rows -> g row + c-term atomicAdd.
//       blocks 512..543: teacher column-sum partials (16 rows each). =====
__global__ __launch_bounds__(1024) void k_fused(
    const float* __restrict__ teacher, const float* __restrict__ center,
    const float* __restrict__ pred, const int* __restrict__ epoch_p,
    float* __restrict__ g_ws, float* __restrict__ part, float* __restrict__ out)
{
    const int bid = blockIdx.x;
    const int t = threadIdx.x;

    if (bid >= 512) {
        // ---- colsum role: 32 blocks x 16 rows, full D per block ----
        const int cb = bid - 512;
        const int d0 = t * 4, d1 = 4096 + t * 4;
        const float* base = teacher + (size_t)cb * 16 * D;
        float4 a0 = make_float4(0.f,0.f,0.f,0.f), a1 = make_float4(0.f,0.f,0.f,0.f);
        #pragma unroll 4
        for (int r = 0; r < 16; ++r) {
            float4 x0 = *(const float4*)(base + (size_t)r * D + d0);
            float4 x1 = *(const float4*)(base + (size_t)r * D + d1);
            a0.x += x0.x; a0.y += x0.y; a0.z += x0.z; a0.w += x0.w;
            a1.x += x1.x; a1.y += x1.y; a1.z += x1.z; a1.w += x1.w;
        }
        *(float4*)(part + (size_t)cb * D + d0) = a0;
        *(float4*)(part + (size_t)cb * D + d1) = a1;
        return;
    }

    const int row = bid;              // 0..511
    const int lane = t & 63, w = t >> 6;   // w: 0..15
    __shared__ float svv[8][16];
    __shared__ int   sii[8][16];
    __shared__ float sred[16][8];

    // ---- load z = teacher - center: 8 elems/thread (cols t*4+{0..3}, 4096+t*4+{0..3}) ----
    const float* trow = teacher + (size_t)row * D;
    const int d0 = t * 4, d1 = 4096 + t * 4;
    float z[8];
    {
        float4 tv0 = *(const float4*)(trow + d0);
        float4 cv0 = *(const float4*)(center + d0);
        float4 tv1 = *(const float4*)(trow + d1);
        float4 cv1 = *(const float4*)(center + d1);
        z[0] = tv0.x - cv0.x; z[1] = tv0.y - cv0.y; z[2] = tv0.z - cv0.z; z[3] = tv0.w - cv0.w;
        z[4] = tv1.x - cv1.x; z[5] = tv1.y - cv1.y; z[6] = tv1.z - cv1.z; z[7] = tv1.w - cv1.w;
    }

    // thread-local argmax cache; code = (t<<3)|j
    float mvl = -INFINITY; int mjl = 0;
    #pragma unroll
    for (int j = 0; j < 8; ++j)
        if (z[j] > mvl) { mvl = z[j]; mjl = j; }

    float topv[8]; int topc[8];
    #pragma unroll 1
    for (int k = 0; k < 8; ++k) {
        float mv = mvl;
        int mc = (t << 3) | mjl;
        #pragma unroll
        for (int o = 32; o > 0; o >>= 1) {
            float ov = __shfl_xor(mv, o, 64);
            int   oc = __shfl_xor(mc, o, 64);
            if (ov > mv) { mv = ov; mc = oc; }
        }
        if (lane == 0) { svv[k][w] = mv; sii[k][w] = mc; }
        __syncthreads();
        float gv = svv[k][0]; int gc = sii[k][0];
        #pragma unroll
        for (int j = 1; j < 16; ++j)
            if (svv[k][j] > gv) { gv = svv[k][j]; gc = sii[k][j]; }
        topv[k] = gv; topc[k] = gc;
        if ((gc >> 3) == t) {
            z[gc & 7] = -INFINITY;
            mvl = -INFINITY; mjl = 0;
            #pragma unroll
            for (int j = 0; j < 8; ++j)
                if (z[j] > mvl) { mvl = z[j]; mjl = j; }
        }
    }

    // ---- weights (computed redundantly per thread, deterministic) ----
    const int e = epoch_p[0];
    const float temp = (e < 30) ? (0.04f + 0.03f * (float)e / 29.0f) : 0.07f;
    float pk[8]; int jk[8];
    float norm = 0.f;
    #pragma unroll
    for (int k = 0; k < 8; ++k) {
        const int to = topc[k] >> 3, j = topc[k] & 7;
        jk[k] = (j < 4) ? (to * 4 + j) : (4096 + to * 4 + (j - 4));
        pk[k] = __expf((topv[k] - topv[0]) / temp);
        norm += pk[k];
    }
    const float invn = 1.0f / norm;
    #pragma unroll
    for (int k = 0; k < 8; ++k) pk[k] *= invn;

    // ---- gather 8 pred rows: g = sum_k pk*P[jk,:], per-row sum-exp (exact lse: 10P bounded) ----
    float4 a0 = make_float4(0.f,0.f,0.f,0.f), a1 = make_float4(0.f,0.f,0.f,0.f);
    float se[8];
    #pragma unroll
    for (int k = 0; k < 8; ++k) {
        const float* prow = pred + (size_t)jk[k] * D;
        float4 x0 = *(const float4*)(prow + d0);
        float4 x1 = *(const float4*)(prow + d1);
        se[k] = __expf(x0.x*10.f) + __expf(x0.y*10.f) + __expf(x0.z*10.f) + __expf(x0.w*10.f)
              + __expf(x1.x*10.f) + __expf(x1.y*10.f) + __expf(x1.z*10.f) + __expf(x1.w*10.f);
        const float p = pk[k];
        a0.x += p*x0.x; a0.y += p*x0.y; a0.z += p*x0.z; a0.w += p*x0.w;
        a1.x += p*x1.x; a1.y += p*x1.y; a1.z += p*x1.z; a1.w += p*x1.w;
    }
    float* grow = g_ws + (size_t)row * D;
    *(float4*)(grow + d0) = a0;
    *(float4*)(grow + d1) = a1;

    #pragma unroll
    for (int k = 0; k < 8; ++k) se[k] = wave_sum(se[k]);
    if (lane == 0) {
        #pragma unroll
        for (int k = 0; k < 8; ++k) sred[w][k] = se[k];
    }
    __syncthreads();
    if (t == 0) {
        float c = 0.f;
        #pragma unroll
        for (int k = 0; k < 8; ++k) {
            float S = 0.f;
            #pragma unroll
            for (int j = 0; j < 16; ++j) S += sred[j][k];
            c += pk[k] * __logf(S);
        }
        const float wgt = (row < 256) ? 7.0f : 6.0f;   // pair multiplicity
        atomicAdd(out, c * wgt * (1.0f / 3328.0f));
    }
}

// ===== K2: block 0 = center/entropies; blocks 1..1792 = student rows 256..2047 =====
__global__ __launch_bounds__(256) void k_main(
    const float* __restrict__ student, const float* __restrict__ g_ws,
    const float* __restrict__ part, const float* __restrict__ center,
    float* __restrict__ out)
{
    const int bid = blockIdx.x;
    const int t = threadIdx.x;
    const int lane = t & 63, w = t >> 6;

    if (bid == 0) {
        // ---- center: batch_center (from 32 partials), EMA, entropies ----
        __shared__ float sm4[4];
        float c[32], bc[32];
        #pragma unroll
        for (int i = 0; i < 8; ++i) {
            const int d = i * 1024 + t * 4;
            float4 cv = *(const float4*)(center + d);
            float4 s = make_float4(0.f, 0.f, 0.f, 0.f);
            for (int rc = 0; rc < 32; ++rc) {
                float4 p = *(const float4*)(part + (size_t)rc * D + d);
                s.x += p.x; s.y += p.y; s.z += p.z; s.w += p.w;
            }
            const float sc = 1.0f / 512.0f;
            bc[i*4+0] = s.x * sc; bc[i*4+1] = s.y * sc;
            bc[i*4+2] = s.z * sc; bc[i*4+3] = s.w * sc;
            c[i*4+0] = cv.x; c[i*4+1] = cv.y; c[i*4+2] = cv.z; c[i*4+3] = cv.w;
            out[3 + d + 0] = cv.x * 0.9f + bc[i*4+0] * 0.1f;
            out[3 + d + 1] = cv.y * 0.9f + bc[i*4+1] * 0.1f;
            out[3 + d + 2] = cv.z * 0.9f + bc[i*4+2] * 0.1f;
            out[3 + d + 3] = cv.w * 0.9f + bc[i*4+3] * 0.1f;
        }

        float mc = -INFINITY, mb = -INFINITY;
        #pragma unroll
        for (int i = 0; i < 32; ++i) { mc = fmaxf(mc, c[i]); mb = fmaxf(mb, bc[i]); }
        #pragma unroll
        for (int o = 32; o > 0; o >>= 1) {
            mc = fmaxf(mc, __shfl_xor(mc, o, 64));
            mb = fmaxf(mb, __shfl_xor(mb, o, 64));
        }
        if (lane == 0) sm4[w] = mc;
        __syncthreads();
        mc = fmaxf(fmaxf(sm4[0], sm4[1]), fmaxf(sm4[2], sm4[3]));
        __syncthreads();
        if (lane == 0) sm4[w] = mb;
        __syncthreads();
        mb = fmaxf(fmaxf(sm4[0], sm4[1]), fmaxf(sm4[2], sm4[3]));
        __syncthreads();

        float zc = 0.f, zb = 0.f;
        #pragma unroll
        for (int i = 0; i < 32; ++i) { zc += __expf(c[i] - mc); zb += __expf(bc[i] - mb); }
        zc = wave_sum(zc); zb = wave_sum(zb);
        if (lane == 0) sm4[w] = zc;
        __syncthreads();
        zc = sm4[0] + sm4[1] + sm4[2] + sm4[3];
        __syncthreads();
        if (lane == 0) sm4[w] = zb;
        __syncthreads();
        zb = sm4[0] + sm4[1] + sm4[2] + sm4[3];
        __syncthreads();
        const float lnZc = __logf(zc);

        float te = 0.f, en = 0.f;
        #pragma unroll
        for (int i = 0; i < 32; ++i) {
            const float lsm = c[i] - mc - lnZc;
            te += __expf(c[i] - mc) * lsm;
            en += __expf(bc[i] - mb) * lsm;
        }
        te = wave_sum(te); en = wave_sum(en);
        if (lane == 0) sm4[w] = te;
        __syncthreads();
        te = sm4[0] + sm4[1] + sm4[2] + sm4[3];
        __syncthreads();
        if (lane == 0) sm4[w] = en;
        __syncthreads();
        en = sm4[0] + sm4[1] + sm4[2] + sm4[3];
        if (t == 0) {
            out[1] = en / zb;
            out[2] = te / zc;
        }
        return;
    }

    // ---- student role: rows 256..2047; no max-subtraction (10*s bounded, exp fits f32) ----
    __shared__ float sred3[4][3];
    const int row = 255 + bid;          // bid 1..1792 -> rows 256..2047
    const int v = row >> 8;             // 1..7
    const int b = row & 255;

    float y[32];
    const float* srow = student + (size_t)row * D;
    #pragma unroll
    for (int i = 0; i < 8; ++i) {
        float4 x = *(const float4*)(srow + i * 1024 + t * 4);
        y[i*4+0] = __expf(x.x * 10.f); y[i*4+1] = __expf(x.y * 10.f);
        y[i*4+2] = __expf(x.z * 10.f); y[i*4+3] = __expf(x.w * 10.f);
    }
    float zs = 0.f;
    #pragma unroll
    for (int i = 0; i < 32; ++i) zs += y[i];

    const float* g0 = g_ws + (size_t)b * D;
    const float* g1 = g_ws + (size_t)(256 + b) * D;
    float a0 = 0.f, a1 = 0.f;
    #pragma unroll
    for (int i = 0; i < 8; ++i) {
        float4 gg = *(const float4*)(g0 + i * 1024 + t * 4);
        a0 += y[i*4+0]*gg.x + y[i*4+1]*gg.y + y[i*4+2]*gg.z + y[i*4+3]*gg.w;
    }
    if (v >= 2) {
        #pragma unroll
        for (int i = 0; i < 8; ++i) {
            float4 gg = *(const float4*)(g1 + i * 1024 + t * 4);
            a1 += y[i*4+0]*gg.x + y[i*4+1]*gg.y + y[i*4+2]*gg.z + y[i*4+3]*gg.w;
        }
    }
    zs = wave_sum(zs); a0 = wave_sum(a0); a1 = wave_sum(a1);
    if (lane == 0) { sred3[w][0] = zs; sred3[w][1] = a0; sred3[w][2] = a1; }
    __syncthreads();
    if (t == 0) {
        const float Z  = sred3[0][0] + sred3[1][0] + sred3[2][0] + sred3[3][0];
        const float A0 = sred3[0][1] + sred3[1][1] + sred3[2][1] + sred3[3][1];
        const float A1 = sred3[0][2] + sred3[1][2] + sred3[2][2] + sred3[3][2];
        const float invZ = 1.0f / Z;
        float term = -10.f * A0 * invZ;
        if (v >= 2) term += -10.f * A1 * invZ;
        atomicAdd(out, term * (1.0f / 3328.0f));
    }
}

extern "C" void kernel_launch(void* const* d_in, const int* in_sizes, int n_in,
                              void* d_out, int out_size, void* d_ws, size_t ws_size,
                              hipStream_t stream) {
    const float* student = (const float*)d_in[0];
    const float* teacher = (const float*)d_in[1];
    const float* pred    = (const float*)d_in[2];
    const float* center  = (const float*)d_in[3];
    const int*   epoch   = (const int*)d_in[4];
    float* out = (float*)d_out;

    float* g_ws = (float*)d_ws;                 // 512*8192 f (16 MB)
    float* part = g_ws + (size_t)512 * D;       // 32*8192 f (1 MB)

    hipMemsetAsync(d_out, 0, sizeof(float), stream);   // zero loss accumulator

    k_fused<<<544, 1024, 0, stream>>>(teacher, center, pred, epoch, g_ws, part, out);
    k_main<<<1793, 256, 0, stream>>>(student, g_ws, part, center, out);
}

// Round 6
// 74.783 us; speedup vs baseline: 1.5598x; 1.5598x over previous
//
#include <hip/hip_runtime.h>
#include <hip/hip_bf16.h>
#include <math.h>

#define D 8192

__device__ __forceinline__ float wave_sum(float v) {
    #pragma unroll
    for (int o = 32; o > 0; o >>= 1) v += __shfl_xor(v, o, 64);
    return v;
}

// ===== K1: blocks 0..511 (512 thr): full-row top-8 -> idx/p; also zero out[0].
//           blocks 512..575: teacher column-sum partials (16 rc x 4 dc). =====
__global__ __launch_bounds__(512) void k_topk_colsum(
    const float* __restrict__ teacher, const float* __restrict__ center,
    const int* __restrict__ epoch_p,
    int* __restrict__ idx_ws, float* __restrict__ p_ws,
    float* __restrict__ part, float* __restrict__ out)
{
    const int bid = blockIdx.x;
    const int t = threadIdx.x;

    if (bid >= 512) {
        // ---- colsum: 64 blocks = 16 row-chunks x 4 col-chunks ----
        const int cb = bid - 512;
        const int rc = cb >> 2, dc = cb & 3;
        const int d0 = dc * 2048 + t * 4;
        const float* base = teacher + (size_t)rc * 32 * D + d0;
        float4 acc = make_float4(0.f, 0.f, 0.f, 0.f);
        #pragma unroll 4
        for (int r = 0; r < 32; ++r) {
            float4 x = *(const float4*)(base + (size_t)r * D);
            acc.x += x.x; acc.y += x.y; acc.z += x.z; acc.w += x.w;
        }
        *(float4*)(part + (size_t)rc * D + d0) = acc;
        return;
    }

    const int row = bid;                 // 0..511
    const int lane = t & 63, w = t >> 6; // w: 0..7
    __shared__ float svv[8][8];
    __shared__ int   sii[8][8];

    if (bid == 0 && t == 0) out[0] = 0.f;   // loss accumulator reset

    // z = teacher - center: 16 elems/thread; col(q,j) = q*2048 + t*4 + j
    const float* trow = teacher + (size_t)row * D;
    float z[16];
    #pragma unroll
    for (int q = 0; q < 4; ++q) {
        const int d = q * 2048 + t * 4;
        float4 tv = *(const float4*)(trow + d);
        float4 cv = *(const float4*)(center + d);
        z[q*4+0] = tv.x - cv.x; z[q*4+1] = tv.y - cv.y;
        z[q*4+2] = tv.z - cv.z; z[q*4+3] = tv.w - cv.w;
    }

    // cached thread-local argmax (i = q*4+j); only popped owner rescans
    float mvl = -INFINITY; int mil = 0;
    #pragma unroll
    for (int i = 0; i < 16; ++i)
        if (z[i] > mvl) { mvl = z[i]; mil = i; }

    float topv[8]; int topcol[8];
    #pragma unroll 1
    for (int k = 0; k < 8; ++k) {
        float mv = mvl;
        int mc = ((mil >> 2) << 11) + t * 4 + (mil & 3);   // column index
        #pragma unroll
        for (int o = 32; o > 0; o >>= 1) {
            float ov = __shfl_xor(mv, o, 64);
            int   oc = __shfl_xor(mc, o, 64);
            if (ov > mv) { mv = ov; mc = oc; }
        }
        if (lane == 0) { svv[k][w] = mv; sii[k][w] = mc; }
        __syncthreads();
        float gv = svv[k][0]; int gc = sii[k][0];
        #pragma unroll
        for (int j = 1; j < 8; ++j)
            if (svv[k][j] > gv) { gv = svv[k][j]; gc = sii[k][j]; }
        topv[k] = gv; topcol[k] = gc;
        if (((gc & 2047) >> 2) == t) {
            z[((gc >> 11) << 2) | (gc & 3)] = -INFINITY;
            mvl = -INFINITY; mil = 0;
            #pragma unroll
            for (int i = 0; i < 16; ++i)
                if (z[i] > mvl) { mvl = z[i]; mil = i; }
        }
    }

    if (t == 0) {
        const int e = epoch_p[0];
        const float temp = (e < 30) ? (0.04f + 0.03f * (float)e / 29.0f) : 0.07f;
        float wgt[8]; float norm = 0.f;
        #pragma unroll
        for (int k = 0; k < 8; ++k) { wgt[k] = __expf((topv[k] - topv[0]) / temp); norm += wgt[k]; }
        const float invn = 1.0f / norm;
        #pragma unroll
        for (int k = 0; k < 8; ++k) {
            p_ws[row * 8 + k] = wgt[k] * invn;
            idx_ws[row * 8 + k] = topcol[k];
        }
    }
}

// ===== K2: gather predictor rows (2048 blocks, 4 col-chunks per teacher row) =====
__global__ __launch_bounds__(256) void k_gather(
    const float* __restrict__ pred, const int* __restrict__ idx_ws,
    const float* __restrict__ p_ws,
    float* __restrict__ g_ws, float* __restrict__ part_lse)
{
    const int bid = blockIdx.x;
    const int t = threadIdx.x;
    const int row = bid >> 2;          // 0..511
    const int ch  = bid & 3;           // 0..3
    const int lane = t & 63, w = t >> 6;
    const int d0 = ch * 2048 + t * 4;
    __shared__ float sred[4][8];

    int jk[8]; float pk[8];
    #pragma unroll
    for (int k = 0; k < 8; ++k) {
        jk[k] = idx_ws[row * 8 + k];
        pk[k] = p_ws[row * 8 + k];
    }

    float4 a0 = make_float4(0.f,0.f,0.f,0.f), a1 = make_float4(0.f,0.f,0.f,0.f);
    float se[8];
    #pragma unroll
    for (int k = 0; k < 8; ++k) {
        const float* prow = pred + (size_t)jk[k] * D;
        float4 x0 = *(const float4*)(prow + d0);
        float4 x1 = *(const float4*)(prow + d0 + 1024);
        // 10*P bounded (~|1.2|) -> plain sum-exp is exact logsumexp
        se[k] = __expf(x0.x*10.f) + __expf(x0.y*10.f) + __expf(x0.z*10.f) + __expf(x0.w*10.f)
              + __expf(x1.x*10.f) + __expf(x1.y*10.f) + __expf(x1.z*10.f) + __expf(x1.w*10.f);
        const float p = pk[k];
        a0.x += p*x0.x; a0.y += p*x0.y; a0.z += p*x0.z; a0.w += p*x0.w;
        a1.x += p*x1.x; a1.y += p*x1.y; a1.z += p*x1.z; a1.w += p*x1.w;
    }
    float* grow = g_ws + (size_t)row * D;
    *(float4*)(grow + d0)        = a0;
    *(float4*)(grow + d0 + 1024) = a1;

    #pragma unroll
    for (int k = 0; k < 8; ++k) se[k] = wave_sum(se[k]);
    if (lane == 0) {
        #pragma unroll
        for (int k = 0; k < 8; ++k) sred[w][k] = se[k];
    }
    __syncthreads();
    if (t < 8)
        part_lse[(size_t)bid * 8 + t] =
            sred[0][t] + sred[1][t] + sred[2][t] + sred[3][t];
}

// ==== K3: blocks 0,1 = c-term finalize->atomic loss; block 2 = center; 3.. = student ====
__global__ __launch_bounds__(256) void k_main(
    const float* __restrict__ student, const float* __restrict__ g_ws,
    const float* __restrict__ p_ws, const float* __restrict__ part_lse,
    const float* __restrict__ part, const float* __restrict__ center,
    float* __restrict__ out)
{
    const int bid = blockIdx.x;
    const int t = threadIdx.x;
    const int lane = t & 63, w = t >> 6;

    if (bid < 2) {
        // ---- c-term finalize: r = bid*256 + t; pair multiplicity 7 (iq=0) or 6 (iq=1) ----
        __shared__ float sm4[4];
        const int r = (bid << 8) | t;
        float c = 0.f;
        #pragma unroll
        for (int k = 0; k < 8; ++k) {
            float s = part_lse[(size_t)(r*4+0)*8+k] + part_lse[(size_t)(r*4+1)*8+k]
                    + part_lse[(size_t)(r*4+2)*8+k] + part_lse[(size_t)(r*4+3)*8+k];
            c += p_ws[r * 8 + k] * __logf(s);
        }
        const float wgt = (bid == 0) ? 7.0f : 6.0f;
        float vv = wave_sum(c * wgt * (1.0f / 3328.0f));
        if (lane == 0) sm4[w] = vv;
        __syncthreads();
        if (t == 0) atomicAdd(out, sm4[0] + sm4[1] + sm4[2] + sm4[3]);
        return;
    }

    if (bid == 2) {
        // ---- center: batch_center, EMA, entropies ----
        __shared__ float sm4[4];
        float c[32], bc[32];
        #pragma unroll
        for (int i = 0; i < 8; ++i) {
            const int d = i * 1024 + t * 4;
            float4 cv = *(const float4*)(center + d);
            float4 s = make_float4(0.f, 0.f, 0.f, 0.f);
            for (int rc = 0; rc < 16; ++rc) {
                float4 p = *(const float4*)(part + (size_t)rc * D + d);
                s.x += p.x; s.y += p.y; s.z += p.z; s.w += p.w;
            }
            const float sc = 1.0f / 512.0f;
            bc[i*4+0] = s.x * sc; bc[i*4+1] = s.y * sc;
            bc[i*4+2] = s.z * sc; bc[i*4+3] = s.w * sc;
            c[i*4+0] = cv.x; c[i*4+1] = cv.y; c[i*4+2] = cv.z; c[i*4+3] = cv.w;
            out[3 + d + 0] = cv.x * 0.9f + bc[i*4+0] * 0.1f;
            out[3 + d + 1] = cv.y * 0.9f + bc[i*4+1] * 0.1f;
            out[3 + d + 2] = cv.z * 0.9f + bc[i*4+2] * 0.1f;
            out[3 + d + 3] = cv.w * 0.9f + bc[i*4+3] * 0.1f;
        }

        float mc = -INFINITY, mb = -INFINITY;
        #pragma unroll
        for (int i = 0; i < 32; ++i) { mc = fmaxf(mc, c[i]); mb = fmaxf(mb, bc[i]); }
        #pragma unroll
        for (int o = 32; o > 0; o >>= 1) {
            mc = fmaxf(mc, __shfl_xor(mc, o, 64));
            mb = fmaxf(mb, __shfl_xor(mb, o, 64));
        }
        if (lane == 0) sm4[w] = mc;
        __syncthreads();
        mc = fmaxf(fmaxf(sm4[0], sm4[1]), fmaxf(sm4[2], sm4[3]));
        __syncthreads();
        if (lane == 0) sm4[w] = mb;
        __syncthreads();
        mb = fmaxf(fmaxf(sm4[0], sm4[1]), fmaxf(sm4[2], sm4[3]));
        __syncthreads();

        float zc = 0.f, zb = 0.f;
        #pragma unroll
        for (int i = 0; i < 32; ++i) { zc += __expf(c[i] - mc); zb += __expf(bc[i] - mb); }
        zc = wave_sum(zc); zb = wave_sum(zb);
        if (lane == 0) sm4[w] = zc;
        __syncthreads();
        zc = sm4[0] + sm4[1] + sm4[2] + sm4[3];
        __syncthreads();
        if (lane == 0) sm4[w] = zb;
        __syncthreads();
        zb = sm4[0] + sm4[1] + sm4[2] + sm4[3];
        __syncthreads();
        const float lnZc = __logf(zc);

        float te = 0.f, en = 0.f;
        #pragma unroll
        for (int i = 0; i < 32; ++i) {
            const float lsm = c[i] - mc - lnZc;
            te += __expf(c[i] - mc) * lsm;
            en += __expf(bc[i] - mb) * lsm;
        }
        te = wave_sum(te); en = wave_sum(en);
        if (lane == 0) sm4[w] = te;
        __syncthreads();
        te = sm4[0] + sm4[1] + sm4[2] + sm4[3];
        __syncthreads();
        if (lane == 0) sm4[w] = en;
        __syncthreads();
        en = sm4[0] + sm4[1] + sm4[2] + sm4[3];
        if (t == 0) {
            out[1] = en / zb;
            out[2] = te / zc;
        }
        return;
    }

    // ---- student role: rows 256..2047; no max-subtraction (10*s bounded, exp fits f32) ----
    __shared__ float sred3[4][3];
    const int row = 253 + bid;          // bid 3..1794 -> rows 256..2047
    const int v = row >> 8;             // 1..7
    const int b = row & 255;

    float y[32];
    const float* srow = student + (size_t)row * D;
    #pragma unroll
    for (int i = 0; i < 8; ++i) {
        float4 x = *(const float4*)(srow + i * 1024 + t * 4);
        y[i*4+0] = __expf(x.x * 10.f); y[i*4+1] = __expf(x.y * 10.f);
        y[i*4+2] = __expf(x.z * 10.f); y[i*4+3] = __expf(x.w * 10.f);
    }
    float zs = 0.f;
    #pragma unroll
    for (int i = 0; i < 32; ++i) zs += y[i];

    const float* g0 = g_ws + (size_t)b * D;
    const float* g1 = g_ws + (size_t)(256 + b) * D;
    float a0 = 0.f, a1 = 0.f;
    #pragma unroll
    for (int i = 0; i < 8; ++i) {
        float4 gg = *(const float4*)(g0 + i * 1024 + t * 4);
        a0 += y[i*4+0]*gg.x + y[i*4+1]*gg.y + y[i*4+2]*gg.z + y[i*4+3]*gg.w;
    }
    if (v >= 2) {
        #pragma unroll
        for (int i = 0; i < 8; ++i) {
            float4 gg = *(const float4*)(g1 + i * 1024 + t * 4);
            a1 += y[i*4+0]*gg.x + y[i*4+1]*gg.y + y[i*4+2]*gg.z + y[i*4+3]*gg.w;
        }
    }
    zs = wave_sum(zs); a0 = wave_sum(a0); a1 = wave_sum(a1);
    if (lane == 0) { sred3[w][0] = zs; sred3[w][1] = a0; sred3[w][2] = a1; }
    __syncthreads();
    if (t == 0) {
        const float Z  = sred3[0][0] + sred3[1][0] + sred3[2][0] + sred3[3][0];
        const float A0 = sred3[0][1] + sred3[1][1] + sred3[2][1] + sred3[3][1];
        const float A1 = sred3[0][2] + sred3[1][2] + sred3[2][2] + sred3[3][2];
        const float invZ = 1.0f / Z;
        float term = -10.f * A0 * invZ;
        if (v >= 2) term += -10.f * A1 * invZ;
        atomicAdd(out, term * (1.0f / 3328.0f));
    }
}

extern "C" void kernel_launch(void* const* d_in, const int* in_sizes, int n_in,
                              void* d_out, int out_size, void* d_ws, size_t ws_size,
                              hipStream_t stream) {
    const float* student = (const float*)d_in[0];
    const float* teacher = (const float*)d_in[1];
    const float* pred    = (const float*)d_in[2];
    const float* center  = (const float*)d_in[3];
    const int*   epoch   = (const int*)d_in[4];
    float* out = (float*)d_out;

    float* g_ws     = (float*)d_ws;                     // 512*8192 f (16 MB)
    float* part     = g_ws + (size_t)512 * D;           // 16*8192 f (512 KB)
    float* p_ws     = part + (size_t)16 * D;            // 512*8 f
    float* part_lse = p_ws + 512 * 8;                   // 2048*8 f
    int*   idx_ws   = (int*)(part_lse + 2048 * 8);      // 512*8 i

    k_topk_colsum<<<576, 512, 0, stream>>>(teacher, center, epoch,
                                           idx_ws, p_ws, part, out);
    k_gather<<<2048, 256, 0, stream>>>(pred, idx_ws, p_ws, g_ws, part_lse);
    k_main<<<1795, 256, 0, stream>>>(student, g_ws, p_ws, part_lse, part, center, out);
}